// Round 2
// baseline (368.928 us; speedup 1.0000x reference)
//
#include <hip/hip_runtime.h>

#define N_NODES 10000
#define N_EDGES 640000
#define D 128
#define BN_EPS 1e-5f
#define TM 32

// ---- Kernel 1: edge scatter-add (fp32 atomics). 2 edges/block, 128 threads/edge ----
__global__ __launch_bounds__(256) void k_scatter(
    const float* __restrict__ x,
    const int* __restrict__ ei,
    float* __restrict__ agg)
{
    const int e = (blockIdx.x << 1) | (threadIdx.x >> 7);
    const int f = threadIdx.x & 127;
    const int s = ei[e];            // src row
    const int d = ei[N_EDGES + e];  // dst row
    atomicAdd(&agg[(size_t)d * D + f], x[(size_t)s * D + f]);
}

// ---- Kernel 2: h = relu((agg + x) @ W + b); write fp32 h to d_out; accumulate BN stats ----
// W staged in LDS fp32 in two half-K phases (rows 0-63, then 64-127) to stay under 64 KB LDS.
__global__ __launch_bounds__(256) void k_mlp(
    const float* __restrict__ agg,
    const float* __restrict__ x,
    const float* __restrict__ W,
    const float* __restrict__ bias,
    float* __restrict__ hout,   // d_out (fp32), pre-BN h
    float* __restrict__ stats)  // [0..127]=sum, [128..255]=sumsq
{
    __shared__ float Ws[64 * D];     // 32 KB: half of W, row-major
    __shared__ float hs[TM][D + 4];  // 16.9 KB: 32 rows of (agg+x), stride 132 (16B aligned)
    const int tid = threadIdx.x;
    const int r0 = blockIdx.x * TM;

    // Stage 32 rows of (agg + x): 1024 float4 groups, 4 per thread
    #pragma unroll
    for (int i = 0; i < 4; i++) {
        const int idx4 = tid + i * 256;        // 0..1023
        const int row  = idx4 >> 5;            // 0..31
        const int c4   = (idx4 & 31) << 2;     // 0,4,..,124
        const int grow = r0 + row;
        float4 v = make_float4(0.f, 0.f, 0.f, 0.f);
        if (grow < N_NODES) {
            const float4 a  = *(const float4*)&agg[(size_t)grow * D + c4];
            const float4 xv = *(const float4*)&x[(size_t)grow * D + c4];
            v.x = a.x + xv.x; v.y = a.y + xv.y; v.z = a.z + xv.z; v.w = a.w + xv.w;
        }
        *(float4*)&hs[row][c4] = v;
    }

    // Thread owns col = tid&127, rows rg*16 .. rg*16+15 (rg = tid>>7)
    const int col = tid & 127;
    const int rg  = tid >> 7;
    float acc[16];
    #pragma unroll
    for (int i = 0; i < 16; i++) acc[i] = 0.f;

    for (int phase = 0; phase < 2; phase++) {
        __syncthreads();  // phase 0: hs staged; phase 1: all reads of Ws(phase 0) done
        // Stage W rows [phase*64, phase*64+64): 2048 float4, 8 per thread
        {
            float4* wd = (float4*)Ws;
            const float4* wsrc = (const float4*)&W[phase * 64 * D];
            #pragma unroll
            for (int i = 0; i < 8; i++)
                wd[tid + i * 256] = wsrc[tid + i * 256];
        }
        __syncthreads();

        for (int kk = 0; kk < 64; kk += 4) {
            const int k = (phase << 6) + kk;
            const float w0 = Ws[(kk + 0) * D + col];  // lanes->consecutive cols: conflict-free
            const float w1 = Ws[(kk + 1) * D + col];
            const float w2 = Ws[(kk + 2) * D + col];
            const float w3 = Ws[(kk + 3) * D + col];
            #pragma unroll
            for (int i = 0; i < 16; i++) {
                const float4 hv = *(const float4*)&hs[rg * 16 + i][k];  // wave broadcast
                float a = acc[i];
                a = fmaf(hv.x, w0, a);
                a = fmaf(hv.y, w1, a);
                a = fmaf(hv.z, w2, a);
                a = fmaf(hv.w, w3, a);
                acc[i] = a;
            }
        }
    }

    // Bias + ReLU + store fp32 h + per-thread stats
    const float bcol = bias[col];
    float s1 = 0.f, s2 = 0.f;
    #pragma unroll
    for (int i = 0; i < 16; i++) {
        const int row = r0 + rg * 16 + i;
        if (row < N_NODES) {
            const float v = fmaxf(acc[i] + bcol, 0.f);
            hout[(size_t)row * D + col] = v;
            s1 += v;
            s2 += v * v;
        }
    }

    // Reduce 2 row-groups per column; one atomic pair per column per block
    __syncthreads();            // everyone done reading hs
    float* red = (float*)hs;    // reuse LDS
    red[tid]       = s1;
    red[256 + tid] = s2;
    __syncthreads();
    if (tid < D) {
        atomicAdd(&stats[tid],     red[tid]       + red[tid + 128]);
        atomicAdd(&stats[D + tid], red[256 + tid] + red[256 + tid + 128]);
    }
}

// ---- Kernel 3: BatchNorm apply in place on d_out (fp32), 4 elems/thread ----
__global__ __launch_bounds__(256) void k_bn(
    float* hout,
    const float* __restrict__ stats,
    const float* __restrict__ gamma,
    const float* __restrict__ beta)
{
    const int idx4 = blockIdx.x * 256 + threadIdx.x;
    const int base = idx4 << 2;           // 0..1,279,996 step 4
    const int c0 = base & (D - 1);
    float4 v = *(const float4*)&hout[base];
    float vv[4] = { v.x, v.y, v.z, v.w };
    float o[4];
    #pragma unroll
    for (int j = 0; j < 4; j++) {
        const int c = c0 + j;
        const float mean = stats[c] * (1.0f / N_NODES);
        const float var  = stats[D + c] * (1.0f / N_NODES) - mean * mean;
        o[j] = (vv[j] - mean) * rsqrtf(var + BN_EPS) * gamma[c] + beta[c];
    }
    *(float4*)&hout[base] = make_float4(o[0], o[1], o[2], o[3]);
}

extern "C" void kernel_launch(void* const* d_in, const int* in_sizes, int n_in,
                              void* d_out, int out_size, void* d_ws, size_t ws_size,
                              hipStream_t stream)
{
    const float* x     = (const float*)d_in[0];  // [10000,128] fp32
    const int*   ei    = (const int*)d_in[1];    // [2,640000] int32
    const float* W     = (const float*)d_in[2];  // [128,128] fp32
    const float* bias  = (const float*)d_in[3];  // [128] fp32
    const float* gamma = (const float*)d_in[4];  // [128] fp32
    const float* beta  = (const float*)d_in[5];  // [128] fp32
    float* out = (float*)d_out;                  // [10000,128] fp32

    // Workspace: agg fp32 [10000*128] then stats fp32 [256]
    float* agg   = (float*)d_ws;
    float* stats = (float*)((char*)d_ws + (size_t)N_NODES * D * sizeof(float));

    // Zero agg + stats (ws is poisoned 0xAA before every call)
    hipMemsetAsync(d_ws, 0, (size_t)N_NODES * D * sizeof(float) + 2 * D * sizeof(float), stream);

    k_scatter<<<N_EDGES / 2, 256, 0, stream>>>(x, ei, agg);
    k_mlp<<<(N_NODES + TM - 1) / TM, 256, 0, stream>>>(agg, x, W, bias, out, stats);
    k_bn<<<(N_NODES * D) / (4 * 256), 256, 0, stream>>>(out, stats, gamma, beta);
}

// Round 3
// 229.750 us; speedup vs baseline: 1.6058x; 1.6058x over previous
//
#include <hip/hip_runtime.h>

#define N_NODES 10000
#define N_EDGES 640000
#define D 128
#define BN_EPS 1e-5f
#define TM 32
#define NPAD 10240   // 256 threads * 40 items in scan

// ---------------- CSR build ----------------

// Histogram of dst degrees: 640K int atomics into 10K counters (L2-resident)
__global__ __launch_bounds__(256) void k_hist(
    const int* __restrict__ ei, int* __restrict__ deg)
{
    const int e = blockIdx.x * 256 + threadIdx.x;
    atomicAdd(&deg[ei[N_EDGES + e]], 1);
}

// Exclusive scan over NPAD degree counts, single block of 256 threads x 40 items.
// Writes both offs[] and a working copy cursor[].
__global__ __launch_bounds__(256) void k_scan(
    const int* __restrict__ deg, int* __restrict__ offs, int* __restrict__ cursor)
{
    __shared__ int part[256];
    const int tid = threadIdx.x;
    const int base = tid * 40;
    int local[40];
    int sum = 0;
    #pragma unroll
    for (int i = 0; i < 40; i++) { local[i] = deg[base + i]; sum += local[i]; }
    part[tid] = sum;
    __syncthreads();
    // Hillis-Steele inclusive scan over 256 partials
    for (int off = 1; off < 256; off <<= 1) {
        int add = (tid >= off) ? part[tid - off] : 0;
        __syncthreads();
        part[tid] += add;
        __syncthreads();
    }
    int run = (tid == 0) ? 0 : part[tid - 1];  // exclusive prefix of this thread's span
    #pragma unroll
    for (int i = 0; i < 40; i++) {
        offs[base + i] = run;
        cursor[base + i] = run;
        run += local[i];
    }
}

// Scatter src ids into CSR order
__global__ __launch_bounds__(256) void k_fill(
    const int* __restrict__ ei, int* __restrict__ cursor, int* __restrict__ ssrc)
{
    const int e = blockIdx.x * 256 + threadIdx.x;
    const int s = ei[e];
    const int d = ei[N_EDGES + e];
    const int pos = atomicAdd(&cursor[d], 1);
    ssrc[pos] = s;
}

// Gather-sum: one wave per node; lane owns float2 column pair.
// pre[i] = x[i] + sum_{j->i} x[j]
__global__ __launch_bounds__(256) void k_gather(
    const float* __restrict__ x,
    const int* __restrict__ offs,
    const int* __restrict__ deg,
    const int* __restrict__ ssrc,
    float* __restrict__ pre)
{
    const int node = blockIdx.x * 4 + (threadIdx.x >> 6);
    const int lane = threadIdx.x & 63;
    const int off = offs[node];
    const int n   = deg[node];
    const float2* __restrict__ x2 = (const float2*)x;

    float2 acc = make_float2(0.f, 0.f);
    int i = 0;
    // Full 64-edge chunks: cooperative index load + shuffle broadcast
    for (; i + 64 <= n; i += 64) {
        const int sj = ssrc[off + i + lane];
        #pragma unroll 16
        for (int t = 0; t < 64; t++) {
            const int s = __shfl(sj, t);
            const float2 v = x2[(size_t)s * 64 + lane];  // 512B coalesced per wave
            acc.x += v.x; acc.y += v.y;
        }
    }
    // Tail
    const int rem = n - i;
    if (rem > 0) {
        const int sj = (lane < rem) ? ssrc[off + i + lane] : 0;
        for (int t = 0; t < rem; t++) {
            const int s = __shfl(sj, t);
            const float2 v = x2[(size_t)s * 64 + lane];
            acc.x += v.x; acc.y += v.y;
        }
    }
    // Fuse the (1+eps)*x term (eps=0)
    const float2 xv = x2[(size_t)node * 64 + lane];
    acc.x += xv.x; acc.y += xv.y;
    ((float2*)pre)[(size_t)node * 64 + lane] = acc;
}

// ---------------- MLP + BN stats ----------------
// h = relu(pre @ W + b); write fp32 h to d_out; accumulate BN sum/sumsq.
__global__ __launch_bounds__(256) void k_mlp(
    const float* __restrict__ pre,
    const float* __restrict__ W,
    const float* __restrict__ bias,
    float* __restrict__ hout,   // d_out (fp32), pre-BN h
    float* __restrict__ stats)  // [0..127]=sum, [128..255]=sumsq
{
    __shared__ float Ws[64 * D];     // 32 KB: half of W, row-major
    __shared__ float hs[TM][D + 4];  // 32 rows of pre, stride 132 (16B aligned)
    const int tid = threadIdx.x;
    const int r0 = blockIdx.x * TM;

    // Stage 32 rows of pre: 1024 float4 groups, 4 per thread
    #pragma unroll
    for (int i = 0; i < 4; i++) {
        const int idx4 = tid + i * 256;        // 0..1023
        const int row  = idx4 >> 5;            // 0..31
        const int c4   = (idx4 & 31) << 2;     // 0,4,..,124
        const int grow = r0 + row;
        float4 v = make_float4(0.f, 0.f, 0.f, 0.f);
        if (grow < N_NODES) v = *(const float4*)&pre[(size_t)grow * D + c4];
        *(float4*)&hs[row][c4] = v;
    }

    const int col = tid & 127;
    const int rg  = tid >> 7;
    float acc[16];
    #pragma unroll
    for (int i = 0; i < 16; i++) acc[i] = 0.f;

    for (int phase = 0; phase < 2; phase++) {
        __syncthreads();
        {
            float4* wd = (float4*)Ws;
            const float4* wsrc = (const float4*)&W[phase * 64 * D];
            #pragma unroll
            for (int i = 0; i < 8; i++)
                wd[tid + i * 256] = wsrc[tid + i * 256];
        }
        __syncthreads();

        for (int kk = 0; kk < 64; kk += 4) {
            const int k = (phase << 6) + kk;
            const float w0 = Ws[(kk + 0) * D + col];
            const float w1 = Ws[(kk + 1) * D + col];
            const float w2 = Ws[(kk + 2) * D + col];
            const float w3 = Ws[(kk + 3) * D + col];
            #pragma unroll
            for (int i = 0; i < 16; i++) {
                const float4 hv = *(const float4*)&hs[rg * 16 + i][k];  // broadcast
                float a = acc[i];
                a = fmaf(hv.x, w0, a);
                a = fmaf(hv.y, w1, a);
                a = fmaf(hv.z, w2, a);
                a = fmaf(hv.w, w3, a);
                acc[i] = a;
            }
        }
    }

    const float bcol = bias[col];
    float s1 = 0.f, s2 = 0.f;
    #pragma unroll
    for (int i = 0; i < 16; i++) {
        const int row = r0 + rg * 16 + i;
        if (row < N_NODES) {
            const float v = fmaxf(acc[i] + bcol, 0.f);
            hout[(size_t)row * D + col] = v;
            s1 += v;
            s2 += v * v;
        }
    }

    __syncthreads();
    float* red = (float*)hs;
    red[tid]       = s1;
    red[256 + tid] = s2;
    __syncthreads();
    if (tid < D) {
        atomicAdd(&stats[tid],     red[tid]       + red[tid + 128]);
        atomicAdd(&stats[D + tid], red[256 + tid] + red[256 + tid + 128]);
    }
}

// ---------------- BatchNorm apply ----------------
__global__ __launch_bounds__(256) void k_bn(
    float* hout,
    const float* __restrict__ stats,
    const float* __restrict__ gamma,
    const float* __restrict__ beta)
{
    const int idx4 = blockIdx.x * 256 + threadIdx.x;
    const int base = idx4 << 2;
    const int c0 = base & (D - 1);
    float4 v = *(const float4*)&hout[base];
    float vv[4] = { v.x, v.y, v.z, v.w };
    float o[4];
    #pragma unroll
    for (int j = 0; j < 4; j++) {
        const int c = c0 + j;
        const float mean = stats[c] * (1.0f / N_NODES);
        const float var  = stats[D + c] * (1.0f / N_NODES) - mean * mean;
        o[j] = (vv[j] - mean) * rsqrtf(var + BN_EPS) * gamma[c] + beta[c];
    }
    *(float4*)&hout[base] = make_float4(o[0], o[1], o[2], o[3]);
}

extern "C" void kernel_launch(void* const* d_in, const int* in_sizes, int n_in,
                              void* d_out, int out_size, void* d_ws, size_t ws_size,
                              hipStream_t stream)
{
    const float* x     = (const float*)d_in[0];  // [10000,128] fp32
    const int*   ei    = (const int*)d_in[1];    // [2,640000] int32
    const float* W     = (const float*)d_in[2];  // [128,128] fp32
    const float* bias  = (const float*)d_in[3];  // [128] fp32
    const float* gamma = (const float*)d_in[4];  // [128] fp32
    const float* beta  = (const float*)d_in[5];  // [128] fp32
    float* out = (float*)d_out;                  // [10000,128] fp32

    // Workspace layout (~7.8 MB):
    // [pre 5.12MB][stats 1KB][deg 40KB][offs 40KB][cursor 40KB][ssrc 2.56MB]
    float* pre    = (float*)d_ws;
    float* stats  = pre + (size_t)N_NODES * D;
    int*   deg    = (int*)(stats + 2 * D);
    int*   offs   = deg + NPAD;
    int*   cursor = offs + NPAD;
    int*   ssrc   = cursor + NPAD;

    // Zero stats + deg (contiguous region)
    hipMemsetAsync(stats, 0, (2 * D + NPAD) * sizeof(int), stream);

    k_hist<<<N_EDGES / 256, 256, 0, stream>>>(ei, deg);
    k_scan<<<1, 256, 0, stream>>>(deg, offs, cursor);
    k_fill<<<N_EDGES / 256, 256, 0, stream>>>(ei, cursor, ssrc);
    k_gather<<<N_NODES / 4, 256, 0, stream>>>(x, offs, deg, ssrc, pre);
    k_mlp<<<(N_NODES + TM - 1) / TM, 256, 0, stream>>>(pre, W, bias, out, stats);
    k_bn<<<(N_NODES * D) / (4 * 256), 256, 0, stream>>>(out, stats, gamma, beta);
}